// Round 11
// baseline (337.241 us; speedup 1.0000x reference)
//
#include <hip/hip_runtime.h>
#include <hip/hip_bf16.h>
#include <math.h>

#define DEV __device__ __forceinline__

constexpr int BATCH = 4096;
constexpr int NBA = 512;    // pool blocks (ka also carries 16 hist blocks)
constexpr int NBB = 4096;   // conv1-stats blocks (1 img each, MFMA)
constexpr int NBC = 4096;   // fused conv blocks (1 img each)
constexpr int NBE = 512;    // fc1 blocks (8 img each)
constexpr int NBW = 16;     // hist slices

// workspace layout (float offsets)
constexpr size_t OFF_POOLED = 0;                            // 4096*196
constexpr size_t OFF_Y2P = OFF_POOLED + (size_t)BATCH*196;  // 4096*400
constexpr size_t OFF_ST1 = OFF_Y2P;                         // 64*4096*4; consumed by kstat1 BEFORE kc writes Y2P
constexpr size_t OFF_H3  = OFF_Y2P + (size_t)BATCH*400;     // 4096*128
constexpr size_t OFF_ST2 = OFF_H3;                          // 16*4096*4; consumed by kstat2 BEFORE ke writes H3
constexpr size_t OFF_W2  = OFF_H3 + (size_t)BATCH*128;      // W2F u16[9][2][2][4][16][8] lane-linear
constexpr size_t OFF_W3  = OFF_W2 + 9216;                   // 51200 [k*128+oc]
constexpr size_t OFF_W4  = OFF_W3 + 51200;                  // 1280 [oc*128+k]
constexpr size_t OFF_WSC = OFF_W4 + 1280;                   // 4 layer scales
constexpr size_t OFF_BN1 = OFF_WSC + 4;                     // 64*4
constexpr size_t OFF_BN2 = OFF_BN1 + 256;                   // 16*4
constexpr size_t OFF_GMM = OFF_BN2 + 64;                    // 8 encoded slots
constexpr size_t OFF_ONS = OFF_GMM + 8;                     // 16 per-slice sum(hw_one)
constexpr size_t OFF_T   = OFF_ONS + 16;                    // (unused)
constexpr size_t OFF_MMA = OFF_T + 4;                       // 512*2 pooled min/max partials
constexpr size_t OFF_HIST= OFF_MMA + 1024;                  // 16*2048 per-slice pass-1 histograms
constexpr size_t OFF_W1M = OFF_HIST + 32768;                // W1F u16[4][2][4][16][8] (2048 floats)
constexpr size_t OFF_SEL = OFF_W1M + 2048;                  // 8 uints: per-L {b0, r1}
constexpr size_t OFF_H2G = OFF_SEL + 8;                     // 4*1024 uints pass-2 global hists
constexpr size_t OFF_H3G = OFF_H2G + 4096;                  // 4*1024 uints pass-3 global hists
// GMM: [0]=pooled min [1]=pooled max [2]=bn1 tmin [3]=bn1 tmax [4]=bn2 tmin [5]=bn2 tmax [6]=fc1 min [7]=fc1 max

typedef __attribute__((ext_vector_type(8))) short bf16x8;
typedef __attribute__((ext_vector_type(4))) float f32x4;

struct InPtrs {
  const float* x;
  const float* sc[4];
  const float* sg[4];
  const float* on[4];
  const float* ze[4];
  const int* qb;
};

// hist-slice partition: 16 slices over 4 layers
__constant__ const int KW_L[16]  ={0,1,1,2,2,2,2,2,2,2,2,2,2,2,2,3};
__constant__ const int KW_S[16]  ={0,0,1,0,1,2,3,4,5,6,7,8,9,10,11,0};
__constant__ const int KW_NB[4]  ={1,2,12,1};
__constant__ const int KW_N[4]   ={576,9216,51200,1280};
__constant__ const int KW_FAN[4] ={9,576,400,128};
__constant__ const int KW_BW0[4] ={0,1,3,15};
__constant__ const int KW_BW1[4] ={1,3,15,16};

DEV unsigned fenc(float f){ unsigned u=__float_as_uint(f); return (u&0x80000000u)? ~u : (u|0x80000000u); }
DEV float fdec(unsigned e){ return __uint_as_float((e&0x80000000u)? (e&0x7fffffffu) : ~e); }
DEV unsigned short f2bf(float f){ unsigned u=__float_as_uint(f); return (unsigned short)((u + 0x7fffu + ((u>>16)&1u))>>16); }

DEV float blk_sum(float v, float* red, int t){
  red[t]=v; __syncthreads();
  for (int s=128;s>0;s>>=1){ if(t<s) red[t]+=red[t+s]; __syncthreads(); }
  float r=red[0]; __syncthreads();
  return r;
}
DEV float blk_min(float v, float* red, int t){
  red[t]=v; __syncthreads();
  for (int s=128;s>0;s>>=1){ if(t<s) red[t]=fminf(red[t],red[t+s]); __syncthreads(); }
  float r=red[0]; __syncthreads();
  return r;
}
DEV float blk_max(float v, float* red, int t){
  red[t]=v; __syncthreads();
  for (int s=128;s>0;s>>=1){ if(t<s) red[t]=fmaxf(red[t],red[t+s]); __syncthreads(); }
  float r=red[0]; __syncthreads();
  return r;
}

// find bucket from top with 256 threads; nbins in {1024,2048}; returns {bucket, remainder}
DEV int2 find256(const int* hist, int nbins, int kk, int t, int* suf, int* sh2){
  const int G=nbins>>8;
  const int lo=t*G;
  int g=0;
  for (int b=0;b<G;++b) g+=hist[lo+b];
  suf[t]=g; __syncthreads();
  for (int s=1;s<256;s<<=1){
    int add=(t+s<256)?suf[t+s]:0;
    __syncthreads();
    suf[t]+=add;
    __syncthreads();
  }
  const int S=suf[t];
  const int Snext=(t<255)?suf[t+1]:0;
  if (S>=kk && Snext<kk){
    int c2=Snext;
    for (int b=lo+G-1;b>=lo;--b){
      c2+=hist[b];
      if (c2>=kk){ sh2[0]=b; sh2[1]=kk-(c2-hist[b]); break; }
    }
  }
  __syncthreads();
  int2 r=make_int2(sh2[0],sh2[1]);
  __syncthreads();
  return r;
}

// ---------------- KA: blocks<512: maxpool + min/max partials (block0 also zeroes pass2/3 hists).
//                    blocks 512..527: per-slice pass-1 histogram + sum(hw_one).
__global__ __launch_bounds__(256) void ka_kernel(InPtrs in, float* __restrict__ ws){
  const int t=threadIdx.x, blk=blockIdx.x;
  __shared__ int h[2048];
  __shared__ float red[256];
  if (blk<NBA){
    if (blk==0){
      unsigned* Z=(unsigned*)(ws+OFF_H2G);
      for (int i=t;i<8192;i+=256) Z[i]=0u;
    }
    const float* x=in.x;
    float* pooled=ws+OFF_POOLED;
    float lmn=3.4e38f, lmx=-3.4e38f;
    for (int p=blk*256+t; p<BATCH*196; p+=NBA*256){
      int b=p/196, r=p-b*196;
      int oy=r/14, ox=r-oy*14;
      const float* px=x+b*784+oy*56+ox*2;
      float m=fmaxf(fmaxf(px[0],px[1]),fmaxf(px[28],px[29]));
      pooled[p]=m;
      lmn=fminf(lmn,m); lmx=fmaxf(lmx,m);
    }
    float bmn=blk_min(lmn,red,t);
    float bmx=blk_max(lmx,red,t);
    if (t==0){ ws[OFF_MMA+blk*2]=bmn; ws[OFF_MMA+blk*2+1]=bmx; }
  } else {
    const int bw=blk-NBA;
    const int L=KW_L[bw], s=KW_S[bw], nb=KW_NB[L];
    const int n4=KW_N[L]>>2;
    const int lo=(int)(((long long)n4*s)/nb), hi=(int)(((long long)n4*(s+1))/nb);
    const float4* sc4=(const float4*)in.sc[L];
    const float4* on4=(const float4*)in.on[L];
    for (int i=t;i<2048;i+=256) h[i]=0;
    __syncthreads();
    float onsum=0.f;
    for (int i=lo+t;i<hi;i+=256){
      float4 v=sc4[i];
      atomicAdd(&h[(__float_as_uint(v.x)&0x7fffffffu)>>20],1);
      atomicAdd(&h[(__float_as_uint(v.y)&0x7fffffffu)>>20],1);
      atomicAdd(&h[(__float_as_uint(v.z)&0x7fffffffu)>>20],1);
      atomicAdd(&h[(__float_as_uint(v.w)&0x7fffffffu)>>20],1);
      float4 o=on4[i];
      onsum+=(o.x+o.y)+(o.z+o.w);
    }
    __syncthreads();
    unsigned* GH=(unsigned*)(ws+OFF_HIST);
    for (int i=t;i<2048;i+=256) GH[bw*2048+i]=(unsigned)h[i];
    float S=blk_sum(onsum,red,t);
    if (t==0) ws[OFF_ONS+bw]=S;
  }
}

// ---------------- KWP2: per-block redundant find1 + pass-2 conditional histogram.
//                  block0 also: pooled reduce + GMM init + W1F zero. (kw2a folded in)
__global__ __launch_bounds__(256) void kwp2_kernel(InPtrs in, float* __restrict__ ws){
  const int t=threadIdx.x, bw=blockIdx.x;
  const int L=KW_L[bw], s=KW_S[bw], nb=KW_NB[L];
  __shared__ int hist[2048];
  __shared__ int suf[256];
  __shared__ int sh2[2];
  __shared__ float redm[256], redx[256];
  if (bw==0){
    float mn=fminf(ws[OFF_MMA+2*t], ws[OFF_MMA+2*(t+256)]);
    float mx=fmaxf(ws[OFF_MMA+2*t+1], ws[OFF_MMA+2*(t+256)+1]);
    redm[t]=mn; redx[t]=mx; __syncthreads();
    for (int st=128;st>0;st>>=1){
      if (t<st){ redm[t]=fminf(redm[t],redm[t+st]); redx[t]=fmaxf(redx[t],redx[t+st]); }
      __syncthreads();
    }
    unsigned* U=(unsigned*)(ws+OFF_GMM);
    if (t==0){ U[0]=fenc(redm[0]); U[1]=fenc(redx[0]); }
    if (t>=2 && t<8) U[t]=(t&1)? 0u : 0xFFFFFFFFu;
    unsigned* z=(unsigned*)(ws+OFF_W1M);     // zero W1F (k>=9 pads)
    for (int i=t;i<2048;i+=256) z[i]=0u;
    __syncthreads();
  }
  // redundant merge of pass-1 hists for L + find (b0,r1) — deterministic, identical per L
  const unsigned* GH=(const unsigned*)(ws+OFF_HIST);
  for (int i=t;i<2048;i+=256){
    int sm2=0;
    for (int b=KW_BW0[L]; b<KW_BW1[L]; ++b) sm2+=(int)GH[b*2048+i];
    hist[i]=sm2;
  }
  __syncthreads();
  int2 f1=find256(hist,2048,KW_N[L]>>1,t,suf,sh2);
  const unsigned b0=(unsigned)f1.x;
  if (s==0 && t==0){
    unsigned* SEL=(unsigned*)(ws+OFF_SEL);
    SEL[L*2]=b0; SEL[L*2+1]=(unsigned)f1.y;
  }
  const int n4=KW_N[L]>>2;
  const int lo=(int)(((long long)n4*s)/nb), hi=(int)(((long long)n4*(s+1))/nb);
  const float4* sc4=(const float4*)in.sc[L];
  unsigned* GH2=(unsigned*)(ws+OFF_H2G)+L*1024;
  for (int i=lo+t;i<hi;i+=256){
    float4 v=sc4[i];
    unsigned ux=__float_as_uint(v.x)&0x7fffffffu;
    unsigned uy=__float_as_uint(v.y)&0x7fffffffu;
    unsigned uz=__float_as_uint(v.z)&0x7fffffffu;
    unsigned uw=__float_as_uint(v.w)&0x7fffffffu;
    if ((ux>>20)==b0) atomicAdd(&GH2[(ux>>10)&1023u],1u);
    if ((uy>>20)==b0) atomicAdd(&GH2[(uy>>10)&1023u],1u);
    if ((uz>>20)==b0) atomicAdd(&GH2[(uz>>10)&1023u],1u);
    if ((uw>>20)==b0) atomicAdd(&GH2[(uw>>10)&1023u],1u);
  }
}

// ---------------- KWP3: per-block find (b1,r2) over hist2, then pass-3 conditional histogram ----------------
__global__ __launch_bounds__(256) void kwp3_kernel(InPtrs in, float* __restrict__ ws){
  const int t=threadIdx.x, bw=blockIdx.x;
  const int L=KW_L[bw], s=KW_S[bw], nb=KW_NB[L];
  const int n4=KW_N[L]>>2;
  const int lo=(int)(((long long)n4*s)/nb), hi=(int)(((long long)n4*(s+1))/nb);
  const unsigned* SEL=(const unsigned*)(ws+OFF_SEL);
  const unsigned b0=SEL[L*2]; const int r1=(int)SEL[L*2+1];
  __shared__ int hist[1024];
  __shared__ int suf[256];
  __shared__ int sh2[2];
  const unsigned* GH2=(const unsigned*)(ws+OFF_H2G)+L*1024;
  for (int i=t;i<1024;i+=256) hist[i]=(int)GH2[i];
  __syncthreads();
  int2 f2=find256(hist,1024,r1,t,suf,sh2);
  const unsigned pre=(b0<<10)|(unsigned)f2.x;
  const float4* sc4=(const float4*)in.sc[L];
  unsigned* GH3=(unsigned*)(ws+OFF_H3G)+L*1024;
  for (int i=lo+t;i<hi;i+=256){
    float4 v=sc4[i];
    unsigned ux=__float_as_uint(v.x)&0x7fffffffu;
    unsigned uy=__float_as_uint(v.y)&0x7fffffffu;
    unsigned uz=__float_as_uint(v.z)&0x7fffffffu;
    unsigned uw=__float_as_uint(v.w)&0x7fffffffu;
    if ((ux>>10)==pre) atomicAdd(&GH3[ux&1023u],1u);
    if ((uy>>10)==pre) atomicAdd(&GH3[uy&1023u],1u);
    if ((uz>>10)==pre) atomicAdd(&GH3[uz&1023u],1u);
    if ((uw>>10)==pre) atomicAdd(&GH3[uw&1023u],1u);
  }
}

// ---------------- KW3: per-block finds -> exact T; slice-parallel weight writes ----------------
__global__ __launch_bounds__(256) void kw3_kernel(InPtrs in, float* __restrict__ ws){
  const int t=threadIdx.x, bw=blockIdx.x;
  const int L=KW_L[bw], s=KW_S[bw], nb=KW_NB[L];
  const int n4=KW_N[L]>>2;
  const int lo=(int)(((long long)n4*s)/nb), hi=(int)(((long long)n4*(s+1))/nb);
  const unsigned* SEL=(const unsigned*)(ws+OFF_SEL);
  const unsigned b0=SEL[L*2]; const int r1=(int)SEL[L*2+1];
  __shared__ int hist[1024];
  __shared__ int suf[256];
  __shared__ int sh2[2];
  const unsigned* GH2=(const unsigned*)(ws+OFF_H2G)+L*1024;
  for (int i=t;i<1024;i+=256) hist[i]=(int)GH2[i];
  __syncthreads();
  int2 f2=find256(hist,1024,r1,t,suf,sh2);
  const unsigned pre=(b0<<10)|(unsigned)f2.x;
  const int r2=f2.y;
  __syncthreads();
  const unsigned* GH3=(const unsigned*)(ws+OFF_H3G)+L*1024;
  for (int i=t;i<1024;i+=256) hist[i]=(int)GH3[i];
  __syncthreads();
  int2 f3=find256(hist,1024,r2,t,suf,sh2);
  const unsigned T=(pre<<10)|(unsigned)f3.x;
  if (s==0 && t==0){
    float os=0.f;
    for (int b=KW_BW0[L]; b<KW_BW1[L]; ++b) os+=ws[OFF_ONS+b];
    ws[OFF_WSC+L]=(os/(float)KW_N[L])*sqrtf((float)KW_FAN[L])*0.5f;
  }
  const float4* sc4=(const float4*)in.sc[L];
  const float4* sg4=(const float4*)in.sg[L];
  const float4* on4=(const float4*)in.on[L];
  const float4* ze4=(const float4*)in.ze[L];
  float* wout=ws+(L==2?OFF_W3:OFF_W4);
  unsigned short* W1F=(unsigned short*)(ws+OFF_W1M);   // [ocT][h][quad][oc16][8]
  unsigned short* W2F=(unsigned short*)(ws+OFF_W2);    // [kykx][s][h][quad][oc16][8]
  for (int i4=lo+t;i4<hi;i4+=256){
    float4 sv4=sc4[i4], g=sg4[i4], o=on4[i4], z=ze4[i4];
    float sv[4]={sv4.x,sv4.y,sv4.z,sv4.w}, gv[4]={g.x,g.y,g.z,g.w};
    float ov[4]={o.x,o.y,o.z,o.w}, zv[4]={z.x,z.y,z.z,z.w};
    #pragma unroll
    for (int j=0;j<4;++j){
      int i=i4*4+j;
      unsigned u=__float_as_uint(sv[j])&0x7fffffffu;
      float w=gv[j]*((u>=T)? ov[j] : zv[j]);
      if (L==0){
        int oc=i/9; int k=i-oc*9;
        int ocT=oc>>4, ocL=oc&15, quad=k>>3, kj=k&7;
        unsigned short hb=f2bf(w);
        float lo2=w-__uint_as_float((unsigned)hb<<16);
        W1F[((((ocT*2+0)*4+quad)*16+ocL)<<3)+kj]=hb;
        W1F[((((ocT*2+1)*4+quad)*16+ocL)<<3)+kj]=f2bf(lo2);
      } else if (L==1){
        int oc=i/576; int r=i-oc*576; int ic=r/9; int kp=r-ic*9;
        int ss=ic>>5, rem=ic&31, quad=rem>>3, kj=rem&7;
        unsigned short hb=f2bf(w);
        float lo2=w-__uint_as_float((unsigned)hb<<16);
        W2F[(((((kp*2+ss)*2+0)*4+quad)*16+oc)<<3)+kj]=hb;
        W2F[(((((kp*2+ss)*2+1)*4+quad)*16+oc)<<3)+kj]=f2bf(lo2);
      } else {
        int o2;
        if (L==2){ int oc=i/400; int kk=i-oc*400; o2=kk*128+oc; }
        else o2=i;
        wout[o2]=w;
      }
    }
  }
}

// ---------------- KB: conv1 via MFMA -> per-channel BN1 stats partials (1 img/block) ----------------
__global__ __launch_bounds__(256) void kb_kernel(InPtrs in, const float* __restrict__ wsr, float* __restrict__ wsw){
  const int t=threadIdx.x, blk=blockIdx.x;
  __shared__ unsigned short qxs[256];
  __shared__ __align__(16) unsigned PAT[2880];   // patches [pos144][20 dwords = 40 u16, k0..31 used]
  __shared__ float xw[1024];
  const float* pooled=wsr+OFF_POOLED;
  const unsigned* U=(const unsigned*)(wsr+OFF_GMM);
  const float mn0=fdec(U[0]);
  const float mx0=fdec(U[1]);
  const float lvf=(float)((1<<in.qb[0])-1);
  const float s0=(mx0-mn0)/lvf, inv_s0=1.0f/s0, zp0=floorf(mn0/s0);
  const float sv=s0/wsr[OFF_WSC+0];
  // zero PAT (covers k>=9 pads), then stage input
  for (int i=t;i<2880;i+=256) PAT[i]=0u;
  if (t<224){
    int row=t>>4, col=t&15;
    float q=0.f;
    if (col<14){ float xx=pooled[(size_t)blk*196+row*14+col]; q=rintf((xx-mn0)*inv_s0)+zp0; }
    qxs[t]=(unsigned short)(__float_as_uint(q)>>16);
  }
  __syncthreads();
  // fill only kd 0..4 (k0=0..8)
  for (int idx=t; idx<720; idx+=256){
    int pos=idx/5, kd=idx-pos*5;
    int py=pos/12, px=pos-py*12;
    int k0=kd*2;
    int ky0=k0/3, kx0=k0-ky0*3;
    unsigned c0=qxs[(py+ky0)*16+px+kx0];
    unsigned c1=0u;
    if (kd<4){ int k1=k0+1; int ky1=k1/3, kx1=k1-ky1*3; c1=qxs[(py+ky1)*16+px+kx1]; }
    PAT[pos*20+kd]=c0|(c1<<16);
  }
  __syncthreads();
  {
    const int w=t>>6, lane=t&63;
    const int l15=lane&15, quad=lane>>4;
    const unsigned short* W1F=(const unsigned short*)(wsr+OFF_W1M);
    const unsigned short* PATu=(const unsigned short*)PAT;
    #pragma unroll
    for (int ocT=0; ocT<4; ++ocT){
      bf16x8 bh=*(const bf16x8*)(W1F+(((ocT*2+0)*64+lane)<<3));
      bf16x8 bl=*(const bf16x8*)(W1F+(((ocT*2+1)*64+lane)<<3));
      float sum=0.f,sq=0.f,mn=3.4e38f,mx=-3.4e38f;
      for (int tl=w; tl<9; tl+=4){
        bf16x8 a=*(const bf16x8*)(PATu+(tl*16+l15)*40+quad*8);
        f32x4 acc=(f32x4){0.f,0.f,0.f,0.f};
        acc=__builtin_amdgcn_mfma_f32_16x16x32_bf16(a,bh,acc,0,0,0);
        acc=__builtin_amdgcn_mfma_f32_16x16x32_bf16(a,bl,acc,0,0,0);
        #pragma unroll
        for (int r=0;r<4;++r){
          float v=acc[r]*sv;
          sum+=v; sq=fmaf(v,v,sq); mn=fminf(mn,v); mx=fmaxf(mx,v);
        }
      }
      #pragma unroll
      for (int d=16;d<64;d<<=1){
        sum+=__shfl_xor(sum,d);
        sq +=__shfl_xor(sq,d);
        mn=fminf(mn,__shfl_xor(mn,d));
        mx=fmaxf(mx,__shfl_xor(mx,d));
      }
      if (quad==0){
        float* p=xw+((w*4+ocT)*16+l15)*4;
        p[0]=sum; p[1]=sq; p[2]=mn; p[3]=mx;
      }
    }
  }
  __syncthreads();
  if (t<64){
    float sum=0.f,sq=0.f,mn=3.4e38f,mx=-3.4e38f;
    #pragma unroll
    for (int w=0;w<4;++w){
      const float* p=xw+((w*4+(t>>4))*16+(t&15))*4;
      sum+=p[0]; sq+=p[1]; mn=fminf(mn,p[2]); mx=fmaxf(mx,p[3]);
    }
    float* p=wsw+OFF_ST1+((size_t)t*NBB+blk)*4;
    p[0]=sum; p[1]=sq; p[2]=mn; p[3]=mx;
  }
}

// ---------------- kstat ----------------
__global__ __launch_bounds__(256) void kstat_kernel(const float* __restrict__ wsr, float* __restrict__ wsw,
                                                    unsigned long long inoff, int nparts, float Nf,
                                                    unsigned long long outoff, int mmslot){
  const int c=blockIdx.x, t=threadIdx.x;
  __shared__ float red[256];
  const float* p=wsr+inoff+(size_t)c*nparts*4;
  float sum=0.f,sq=0.f,mn=3.4e38f,mx=-3.4e38f;
  for (int i=t;i<nparts;i+=256){
    sum+=p[i*4]; sq+=p[i*4+1];
    mn=fminf(mn,p[i*4+2]); mx=fmaxf(mx,p[i*4+3]);
  }
  float S=blk_sum(sum,red,t);
  float Q=blk_sum(sq,red,t);
  float MN=blk_min(mn,red,t);
  float MX=blk_max(mx,red,t);
  if (t==0){
    float mean=S/Nf;
    float var=fmaxf(Q/Nf-mean*mean,0.f);
    float sd=sqrtf(var+1e-5f);
    float* o=wsw+outoff+c*4;
    float tmn=(MN-mean)/sd, tmx=(MX-mean)/sd;
    o[0]=mean; o[1]=sd; o[2]=tmn; o[3]=tmx;
    unsigned* U=(unsigned*)(wsw+OFF_GMM);
    atomicMin(&U[mmslot],fenc(tmn));
    atomicMax(&U[mmslot+1],fenc(tmx));
  }
}

// ---------------- KC: conv1(MFMA)->bn1/relu/quant->conv2(MFMA)->pool, 1 img/block ----------------
__global__ __launch_bounds__(256) void kc_kernel(InPtrs in, const float* __restrict__ wsr, float* __restrict__ wsw){
  const int t=threadIdx.x, blk=blockIdx.x;
  __shared__ unsigned short qxs[256];
  __shared__ __align__(16) unsigned PAT[2880];           // patches; aliased by c2s after conv1
  __shared__ __align__(16) unsigned short actA[144*72];  // [cell][72: 64 ch + 8 pad] bf16 codes
  __shared__ float sA2[64], sB2[64];
  __shared__ float stsum[16], stsq[16];
  __shared__ unsigned stmn[16], stmx[16];
  float* c2s=(float*)PAT;                                // [oc16][100] conv2 out
  const float* pooled=wsr+OFF_POOLED;
  const unsigned* U=(const unsigned*)(wsr+OFF_GMM);
  const float mn0=fdec(U[0]);
  const float mx0=fdec(U[1]);
  const float rmn=fdec(U[2]);
  const float rmx=fdec(U[3]);
  const float lvf=(float)((1<<in.qb[0])-1);
  const float s0=(mx0-mn0)/lvf, inv_s0=1.0f/s0, zp0=floorf(mn0/s0);
  const float s1w=wsr[OFF_WSC+0], s2w=wsr[OFF_WSC+1];
  const float s2=(fmaxf(rmx,0.f)-fmaxf(rmn,0.f))/lvf;
  const float inv_s2=1.0f/s2;
  const float g2=s2/s2w;
  if (t<64){
    float m=wsr[OFF_BN1+t*4], sd=wsr[OFF_BN1+t*4+1];
    sA2[t]=(s0/(s1w*sd))*inv_s2;     // inv_s2 folded: code = rint(max(fma(acc,a2,b2),0))
    sB2[t]=(-m/sd)*inv_s2;
  }
  if (t<16){ stsum[t]=0.f; stsq[t]=0.f; stmn[t]=0xFFFFFFFFu; stmx[t]=0u; }
  for (int i=t;i<2880;i+=256) PAT[i]=0u;   // zero (covers k>=9 pads)
  if (t<224){
    int row=t>>4, col=t&15;
    float q=0.f;
    if (col<14){ float xx=pooled[(size_t)blk*196+row*14+col]; q=rintf((xx-mn0)*inv_s0)+zp0; }
    qxs[t]=(unsigned short)(__float_as_uint(q)>>16);
  }
  __syncthreads();
  // fill only kd 0..4
  for (int idx=t; idx<720; idx+=256){
    int pos=idx/5, kd=idx-pos*5;
    int py=pos/12, px=pos-py*12;
    int k0=kd*2;
    int ky0=k0/3, kx0=k0-ky0*3;
    unsigned c0=qxs[(py+ky0)*16+px+kx0];
    unsigned c1=0u;
    if (kd<4){ int k1=k0+1; int ky1=k1/3, kx1=k1-ky1*3; c1=qxs[(py+ky1)*16+px+kx1]; }
    PAT[pos*20+kd]=c0|(c1<<16);
  }
  __syncthreads();
  // conv1 MFMA + bn/relu/quant -> actA (paired dword writes via shfl)
  {
    const int w=t>>6, lane=t&63;
    const int l15=lane&15, quad=lane>>4;
    const unsigned short* W1F=(const unsigned short*)(wsr+OFF_W1M);
    const unsigned short* PATu=(const unsigned short*)PAT;
    unsigned* actAd=(unsigned*)actA;
    #pragma unroll
    for (int ocT=0; ocT<4; ++ocT){
      bf16x8 bh=*(const bf16x8*)(W1F+(((ocT*2+0)*64+lane)<<3));
      bf16x8 bl=*(const bf16x8*)(W1F+(((ocT*2+1)*64+lane)<<3));
      const int oc=ocT*16+l15;
      const float a2=sA2[oc], b2=sB2[oc];
      const int ocp=ocT*8+(l15>>1);
      for (int tl=w; tl<9; tl+=4){
        bf16x8 a=*(const bf16x8*)(PATu+(tl*16+l15)*40+quad*8);
        f32x4 acc=(f32x4){0.f,0.f,0.f,0.f};
        acc=__builtin_amdgcn_mfma_f32_16x16x32_bf16(a,bh,acc,0,0,0);
        acc=__builtin_amdgcn_mfma_f32_16x16x32_bf16(a,bl,acc,0,0,0);
        #pragma unroll
        for (int r=0;r<4;++r){
          int pos=tl*16+quad*4+r;
          float f=fminf(rintf(fmaxf(fmaf(acc[r],a2,b2),0.f)),lvf);
          unsigned fv=__float_as_uint(f);
          unsigned pv=(unsigned)__shfl_xor((int)fv,1);
          if ((lane&1)==0){
            actAd[pos*36+ocp]=(fv>>16)|(pv&0xffff0000u);
          }
        }
      }
    }
  }
  __syncthreads();
  // conv2 via MFMA: 7 M-tiles of 16 positions; wave w gets tau=w, w+4
  {
    const int w=t>>6, lane=t&63;
    const int oc=lane&15, quad=lane>>4;
    const unsigned short* W2F=(const unsigned short*)(wsr+OFF_W2);
    const int nT=(w<3)?2:1;
    int abase[2]; int taus[2];
    for (int i=0;i<nT;++i){
      int tau=w+i*4;
      int posb=tau*16+(lane&15);
      int pc=posb>99?99:posb;
      int py=pc/10, px=pc-py*10;
      abase[i]=(py*12+px)*72+quad*8;
      taus[i]=tau;
    }
    f32x4 acc[2];
    acc[0]=(f32x4){0.f,0.f,0.f,0.f};
    acc[1]=(f32x4){0.f,0.f,0.f,0.f};
    #pragma unroll 1
    for (int kykx=0;kykx<9;++kykx){
      const int co=((kykx/3)*12+(kykx%3))*72;
      #pragma unroll
      for (int s=0;s<2;++s){
        bf16x8 bh=*(const bf16x8*)(W2F+((((kykx*2+s)*2+0)*64+lane)<<3));
        bf16x8 bl=*(const bf16x8*)(W2F+((((kykx*2+s)*2+1)*64+lane)<<3));
        #pragma unroll
        for (int i=0;i<2;++i){
          if (i<nT){
            bf16x8 a=*(const bf16x8*)(actA+abase[i]+co+s*32);
            acc[i]=__builtin_amdgcn_mfma_f32_16x16x32_bf16(a,bh,acc[i],0,0,0);
            acc[i]=__builtin_amdgcn_mfma_f32_16x16x32_bf16(a,bl,acc[i],0,0,0);
          }
        }
      }
    }
    __syncthreads();   // PAT + actA reads done -> safe to write c2s (aliases PAT)
    for (int i=0;i<nT;++i){
      int pos4=taus[i]*16+quad*4;
      if (pos4<100){
        float4* dst=(float4*)&c2s[oc*100+pos4];
        *dst=make_float4(acc[i].x*g2,acc[i].y*g2,acc[i].z*g2,acc[i].w*g2);
      }
    }
  }
  __syncthreads();
  for (int i=t;i<400;i+=256){
    int ch=i/25, pp=i-ch*25;
    int py=pp/5, px=pp-py*5;
    const float* cc=c2s+ch*100;
    int base=py*20+px*2;
    float v=fmaxf(fmaxf(cc[base],cc[base+1]),fmaxf(cc[base+10],cc[base+11]));
    wsw[OFF_Y2P+(size_t)blk*400+i]=v;
    atomicAdd(&stsum[ch],v);
    atomicAdd(&stsq[ch],v*v);
    atomicMin(&stmn[ch],fenc(v));
    atomicMax(&stmx[ch],fenc(v));
  }
  __syncthreads();
  if (t<16){
    float* p=wsw+OFF_ST2+((size_t)t*NBC+blk)*4;
    p[0]=stsum[t]; p[1]=stsq[t]; p[2]=fdec(stmn[t]); p[3]=fdec(stmx[t]);
  }
}

// ---------------- KE: bn2/relu/quant -> fc1 -> relu, 8 img/block (2 img/wave) ----------------
__global__ __launch_bounds__(256) void ke_kernel(InPtrs in, const float* __restrict__ wsr, float* __restrict__ wsw){
  const int t=threadIdx.x, blk=blockIdx.x;
  __shared__ __align__(16) float xs[3200];
  __shared__ float sm[16], sisd[16];
  const unsigned* U=(const unsigned*)(wsr+OFF_GMM);
  const float lvf=(float)((1<<in.qb[0])-1);
  const float rmn=fdec(U[4]);
  const float rmx=fdec(U[5]);
  if (t<16){ sm[t]=wsr[OFF_BN2+t*4]; sisd[t]=1.0f/wsr[OFF_BN2+t*4+1]; }
  const float s3=(fmaxf(rmx,0.f)-fmaxf(rmn,0.f))/lvf;
  const float inv_s3=1.0f/s3;
  const float inv_s3w=1.0f/wsr[OFF_WSC+2];
  const int b0=blk*8;
  __syncthreads();
  for (int i=t;i<3200;i+=256){
    int img=i/400, k=i-img*400;
    int ch=k/25;
    float y=wsr[OFF_Y2P+(size_t)(b0+img)*400+k];
    float bn=(y-sm[ch])*sisd[ch];
    float r=fmaxf(bn,0.f);
    xs[i]=fminf(rintf(r*inv_s3),lvf)*s3;
  }
  __syncthreads();
  const int w=t>>6, lane=t&63;
  const float* xA=xs+(w*2)*400;
  const float* xB=xs+(w*2+1)*400;
  const float* w3=wsr+OFF_W3;
  float aA0=0.f,aA1=0.f,aB0=0.f,aB1=0.f;
  #pragma unroll 2
  for (int k=0;k<400;k+=4){
    float4 va=*(const float4*)(xA+k);
    float4 vb=*(const float4*)(xB+k);
    float2 w0=*(const float2*)(w3+(k+0)*128+lane*2);
    float2 w1=*(const float2*)(w3+(k+1)*128+lane*2);
    float2 w2=*(const float2*)(w3+(k+2)*128+lane*2);
    float2 wv3=*(const float2*)(w3+(k+3)*128+lane*2);
    aA0=fmaf(va.x,w0.x,aA0); aA1=fmaf(va.x,w0.y,aA1);
    aB0=fmaf(vb.x,w0.x,aB0); aB1=fmaf(vb.x,w0.y,aB1);
    aA0=fmaf(va.y,w1.x,aA0); aA1=fmaf(va.y,w1.y,aA1);
    aB0=fmaf(vb.y,w1.x,aB0); aB1=fmaf(vb.y,w1.y,aB1);
    aA0=fmaf(va.z,w2.x,aA0); aA1=fmaf(va.z,w2.y,aA1);
    aB0=fmaf(vb.z,w2.x,aB0); aB1=fmaf(vb.z,w2.y,aB1);
    aA0=fmaf(va.w,wv3.x,aA0); aA1=fmaf(va.w,wv3.y,aA1);
    aB0=fmaf(vb.w,wv3.x,aB0); aB1=fmaf(vb.w,wv3.y,aB1);
  }
  float hA0=fmaxf(aA0*inv_s3w,0.f), hA1=fmaxf(aA1*inv_s3w,0.f);
  float hB0=fmaxf(aB0*inv_s3w,0.f), hB1=fmaxf(aB1*inv_s3w,0.f);
  *(float2*)(wsw+OFF_H3+(size_t)(b0+w*2)*128+lane*2)=make_float2(hA0,hA1);
  *(float2*)(wsw+OFF_H3+(size_t)(b0+w*2+1)*128+lane*2)=make_float2(hB0,hB1);
  float hmn=fminf(fminf(hA0,hA1),fminf(hB0,hB1));
  float hmx=fmaxf(fmaxf(hA0,hA1),fmaxf(hB0,hB1));
  #pragma unroll
  for (int d=1;d<64;d<<=1){
    hmn=fminf(hmn,__shfl_xor(hmn,d));
    hmx=fmaxf(hmx,__shfl_xor(hmx,d));
  }
  if (lane==0){
    unsigned* Uw=(unsigned*)(wsw+OFF_GMM);
    atomicMin(&Uw[6],fenc(hmn));
    atomicMax(&Uw[7],fenc(hmx));
  }
}

// ---------------- KF: quant -> fc2 -> log_softmax; 64 rows/block, 4 lanes/row ----------------
__global__ __launch_bounds__(256) void kf_kernel(InPtrs in, const float* __restrict__ wsr, float* __restrict__ out){
  const int t=threadIdx.x, blk=blockIdx.x;
  __shared__ float w4s[1280];
  const unsigned* U=(const unsigned*)(wsr+OFF_GMM);
  const float lvf=(float)((1<<in.qb[0])-1);
  const float hmn=fdec(U[6]);
  const float hmx=fdec(U[7]);
  for (int i=t;i<1280;i+=256) w4s[i]=wsr[OFF_W4+i];
  const float s4=(hmx-hmn)/lvf;
  const float inv_s4=1.0f/s4;
  const float inv_s4w=1.0f/wsr[OFF_WSC+3];
  __syncthreads();
  const int row=blk*64+(t>>2), l4=t&3;
  const float4* hr4=(const float4*)(wsr+OFF_H3+(size_t)row*128);
  float acc[10];
  #pragma unroll
  for (int j=0;j<10;++j) acc[j]=0.f;
  #pragma unroll 2
  for (int j=0;j<8;++j){
    float4 v=hr4[l4*8+j];
    int kb=(l4*8+j)*4;
    float q0=fminf(rintf(v.x*inv_s4),lvf)*s4;
    float q1=fminf(rintf(v.y*inv_s4),lvf)*s4;
    float q2=fminf(rintf(v.z*inv_s4),lvf)*s4;
    float q3=fminf(rintf(v.w*inv_s4),lvf)*s4;
    #pragma unroll
    for (int o=0;o<10;++o){
      const float* wr=w4s+o*128+kb;
      acc[o]=fmaf(q0,wr[0],acc[o]);
      acc[o]=fmaf(q1,wr[1],acc[o]);
      acc[o]=fmaf(q2,wr[2],acc[o]);
      acc[o]=fmaf(q3,wr[3],acc[o]);
    }
  }
  #pragma unroll
  for (int o=0;o<10;++o){
    acc[o]+=__shfl_xor(acc[o],1);
    acc[o]+=__shfl_xor(acc[o],2);
  }
  if (l4==0){
    float mx=-3.4e38f;
    #pragma unroll
    for (int o=0;o<10;++o){ acc[o]*=inv_s4w; mx=fmaxf(mx,acc[o]); }
    float se=0.f;
    #pragma unroll
    for (int o=0;o<10;++o) se+=expf(acc[o]-mx);
    const float ls=logf(se);
    #pragma unroll
    for (int o=0;o<10;++o) out[row*10+o]=acc[o]-mx-ls;
  }
}

extern "C" void kernel_launch(void* const* d_in, const int* in_sizes, int n_in,
                              void* d_out, int out_size, void* d_ws, size_t ws_size,
                              hipStream_t stream){
  (void)in_sizes; (void)n_in; (void)out_size; (void)ws_size;
  InPtrs P;
  P.x=(const float*)d_in[0];
  for (int l=0;l<4;++l){
    P.sc[l]=(const float*)d_in[1+l*4];
    P.sg[l]=(const float*)d_in[2+l*4];
    P.on[l]=(const float*)d_in[3+l*4];
    P.ze[l]=(const float*)d_in[4+l*4];
  }
  P.qb=(const int*)d_in[17];
  float* ws=(float*)d_ws;

  hipLaunchKernelGGL(ka_kernel,   dim3(NBA+NBW), dim3(256), 0, stream, P, ws);
  hipLaunchKernelGGL(kwp2_kernel, dim3(NBW),     dim3(256), 0, stream, P, ws);
  hipLaunchKernelGGL(kwp3_kernel, dim3(NBW),     dim3(256), 0, stream, P, ws);
  hipLaunchKernelGGL(kw3_kernel,  dim3(NBW),     dim3(256), 0, stream, P, ws);
  hipLaunchKernelGGL(kb_kernel,   dim3(NBB),     dim3(256), 0, stream, P, ws, ws);
  hipLaunchKernelGGL(kstat_kernel, dim3(64), dim3(256), 0, stream, ws, ws,
                     (unsigned long long)OFF_ST1, NBB, 4096.f*144.f, (unsigned long long)OFF_BN1, 2);
  hipLaunchKernelGGL(kc_kernel,   dim3(NBC),     dim3(256), 0, stream, P, ws, ws);
  hipLaunchKernelGGL(kstat_kernel, dim3(16), dim3(256), 0, stream, ws, ws,
                     (unsigned long long)OFF_ST2, NBC, 4096.f*25.f, (unsigned long long)OFF_BN2, 4);
  hipLaunchKernelGGL(ke_kernel,   dim3(NBE),     dim3(256), 0, stream, P, ws, ws);
  hipLaunchKernelGGL(kf_kernel,   dim3(64),      dim3(256), 0, stream, P, ws, (float*)d_out);
}